// Round 6
// baseline (260.082 us; speedup 1.0000x reference)
//
#include <hip/hip_runtime.h>
#include <hip/hip_bf16.h>
#include <stdint.h>

// ---------------------------------------------------------------------------
// LocalAttentionBlock: B=2, L=2048, D=2048, H=16 (MQA, 1 KV head), hd=128,
// rope dims=64, window=512.
// R10 (resubmit; prior round was a broker timeout, no measurement): GEMM
// cores switched to mfma_f32_32x32x16_bf16 (half the MFMA instr count per
// FLOP; 2382 vs 2075 TF ubench ceiling). R5 shell: 128x128 tile, 4 waves
// (2x2) of 64x64 (= 2x2 frags of 32x32), BK=64, single-buffered 2-barrier
// loop, 32 KB LDS, XCD remap. LDS rows are 64-elem contiguous with
// chunk^(row&7) XOR swizzle (G4 pattern), staged via pre-swizzled global src.
// Epilogues rewritten for the 32x32 C/D layout: col=lane&31,
// row=(reg&3)+8*(reg>>2)+4*(lane>>5). attn_mfma / prep_all unchanged (R8).
// ---------------------------------------------------------------------------

typedef float  f32x4   __attribute__((ext_vector_type(4)));
typedef float  f32x16  __attribute__((ext_vector_type(16)));
typedef __bf16 bf16x8  __attribute__((ext_vector_type(8)));

#define ASYNC_LD16(gp, lp)                                                     \
  __builtin_amdgcn_global_load_lds(                                            \
      (__attribute__((address_space(1))) void*)(gp),                           \
      (__attribute__((address_space(3))) void*)(lp), 16, 0, 0)

// ---------------------------------------------------------------------------
// Fused prep: blocks [0,8192) convert x -> bf16; blocks [8192,16896) do the
// four weight transposes (fp32 [R][C] -> bf16 [C][R]).
// ---------------------------------------------------------------------------
__global__ __launch_bounds__(256) void prep_all(
    const float* __restrict__ x, __hip_bfloat16* __restrict__ xb,
    const float* __restrict__ Wq, const float* __restrict__ Wk,
    const float* __restrict__ Wv, const float* __restrict__ Wo,
    __hip_bfloat16* __restrict__ wqkvT, __hip_bfloat16* __restrict__ woT) {
  __shared__ float t[32][33];
  int bid = blockIdx.x;
  if (bid < 8192) {
    const int i = bid * 256 + threadIdx.x;
    const float4 v = ((const float4*)x)[i];
    __align__(8) __hip_bfloat16 o[4] = {
        __float2bfloat16(v.x), __float2bfloat16(v.y),
        __float2bfloat16(v.z), __float2bfloat16(v.w)};
    *(uint2*)(xb + (size_t)i * 4) = *(uint2*)o;
    return;
  }
  bid -= 8192;
  const float* src;
  __hip_bfloat16* dst;
  int C, cb, rb;
  if (bid < 4096) {
    src = Wq; dst = wqkvT; C = 2048; cb = bid & 63; rb = bid >> 6;
  } else if (bid < 4352) {
    const int l = bid - 4096;
    src = Wk; dst = wqkvT + 2048ull * 2048; C = 128; cb = l & 3; rb = l >> 2;
  } else if (bid < 4608) {
    const int l = bid - 4352;
    src = Wv; dst = wqkvT + 2176ull * 2048; C = 128; cb = l & 3; rb = l >> 2;
  } else {
    const int l = bid - 4608;
    src = Wo; dst = woT; C = 2048; cb = l & 63; rb = l >> 6;
  }
  const int c0 = cb * 32, r0 = rb * 32;
  const int xx = threadIdx.x & 31, y = threadIdx.x >> 5;
#pragma unroll
  for (int i = 0; i < 32; i += 8)
    t[y + i][xx] = src[(size_t)(r0 + y + i) * C + c0 + xx];
  __syncthreads();
#pragma unroll
  for (int i = 0; i < 32; i += 8)
    dst[(size_t)(c0 + y + i) * 2048 + r0 + xx] = __float2bfloat16(t[xx][y + i]);
}

// Bijective XCD swizzle (grid % 8 == 0: 576 and 512).
__device__ __forceinline__ void xcd_remap(int& bx, int& by) {
  const int nwg = gridDim.x * gridDim.y;
  const int flat = blockIdx.y * gridDim.x + blockIdx.x;
  const int cpx = nwg >> 3;
  const int nid = (flat & 7) * cpx + (flat >> 3);
  bx = nid % gridDim.x;
  by = nid / gridDim.x;
}

// ---------------------------------------------------------------------------
// R10 GEMM core: 128x128 tile, 4 waves (2x2), each wave 64x64 as 2x2 frags
// of 32x32x16 MFMA. BK=64 = 4 K-steps of 16. LDS: A/B each [128][64] bf16
// (16 KB), rows contiguous, chunk^(row&7) XOR swizzle. 16 b128 reads + 16
// MFMAs per wave per BK (vs 16 reads + 32 MFMAs with 16x16x32).
// ---------------------------------------------------------------------------
__device__ __forceinline__ void gemm_core32(const __bf16* __restrict__ A,
                                            const __bf16* __restrict__ BT,
                                            int K, int m0, int n0, __bf16* As,
                                            __bf16* Bs, f32x16 (&acc)[2][2]) {
  const int tid = threadIdx.x;
  const int wave = tid >> 6;          // 0..3
  const int lane = tid & 63;
  const int wm = (wave & 1) * 64;     // wave row group
  const int wn = (wave >> 1) * 64;    // wave col group
  const int l5 = lane & 31;           // frag row/col
  const int half = lane >> 5;         // k-half selector

  // Staging: 1024 chunks of 8 elems per operand (128 rows x 8 chunks).
  // LDS linear slot c holds global chunk c ^ (row&7)  (involution).
  size_t goff[4];
  int ldso[4];
#pragma unroll
  for (int i = 0; i < 4; i++) {
    const int cidx = i * 256 + tid;   // [0,1024)
    const int row = cidx >> 3;        // [0,128)
    const int c = cidx & 7;
    const int cg = c ^ (row & 7);
    goff[i] = (size_t)row * K + cg * 8;
    ldso[i] = cidx * 8;               // = row*64 + c*8
  }
  const __bf16* Abase = A + (size_t)m0 * K;
  const __bf16* Bbase = BT + (size_t)n0 * K;

  for (int k0 = 0; k0 < K; k0 += 64) {
#pragma unroll
    for (int i = 0; i < 4; i++)
      ASYNC_LD16(Abase + k0 + goff[i], As + ldso[i]);
#pragma unroll
    for (int i = 0; i < 4; i++)
      ASYNC_LD16(Bbase + k0 + goff[i], Bs + ldso[i]);
    __syncthreads();
    // Frag reads: lane l -> row (l&31), k = s*16 + (l>>5)*8 .. +7
    // global chunk = s*2 + half, at LDS slot (s*2+half) ^ (row&7).
    bf16x8 af[2][4], bf[2][4];
#pragma unroll
    for (int fi = 0; fi < 2; fi++) {
      const int row = wm + fi * 32 + l5;
      const int sw = row & 7;
#pragma unroll
      for (int s = 0; s < 4; s++)
        af[fi][s] = *(const bf16x8*)&As[row * 64 + ((s * 2 + half) ^ sw) * 8];
    }
#pragma unroll
    for (int fj = 0; fj < 2; fj++) {
      const int row = wn + fj * 32 + l5;
      const int sw = row & 7;
#pragma unroll
      for (int s = 0; s < 4; s++)
        bf[fj][s] = *(const bf16x8*)&Bs[row * 64 + ((s * 2 + half) ^ sw) * 8];
    }
#pragma unroll
    for (int s = 0; s < 4; s++)
#pragma unroll
      for (int fi = 0; fi < 2; fi++)
#pragma unroll
        for (int fj = 0; fj < 2; fj++)
          acc[fi][fj] = __builtin_amdgcn_mfma_f32_32x32x16_bf16(
              af[fi][s], bf[fj][s], acc[fi][fj], 0, 0, 0);
    __syncthreads();
  }
}

// ---------------------------------------------------------------------------
// QKV GEMM, fused epilogues. N=2304: n0<2048 -> q head (rope), n0==2048 -> k
// (rope), n0==2176 -> v written TRANSPOSED to vtd [b][128][2048].
// 32x32 C/D layout: col = wn + fj*32 + (lane&31),
//                   row = wm + fi*32 + (v&3) + 8*(v>>2) + 4*(lane>>5).
// ---------------------------------------------------------------------------
__global__ __launch_bounds__(256) void gemm_qkv(
    const __bf16* __restrict__ A, const __bf16* __restrict__ BT,
    __hip_bfloat16* __restrict__ qd, __hip_bfloat16* __restrict__ kd,
    __hip_bfloat16* __restrict__ vtd, int K) {
  __shared__ __align__(16) __bf16 As[128 * 64];
  __shared__ __align__(16) __bf16 Bs[128 * 64];
  int bx, by;
  xcd_remap(bx, by);
  const int m0 = by * 128;
  const int n0 = bx * 128;
  f32x16 acc[2][2];
#pragma unroll
  for (int i = 0; i < 2; i++)
#pragma unroll
    for (int j = 0; j < 2; j++)
#pragma unroll
      for (int e = 0; e < 16; e++) acc[i][j][e] = 0.f;
  gemm_core32(A, BT, K, m0, n0, As, Bs, acc);

  const int tid = threadIdx.x;
  const int wave = tid >> 6;
  const int lane = tid & 63;
  const int l5 = lane & 31;
  const int half = lane >> 5;
  const int wm = (wave & 1) * 64;
  const int wn = (wave >> 1) * 64;

  if (n0 == 2176) {  // V: transposed write, no rope
    const int bb = m0 >> 11;
    const int mloc = m0 & 2047;
#pragma unroll
    for (int fi = 0; fi < 2; fi++) {
#pragma unroll
      for (int fj = 0; fj < 2; fj++) {
        const int col = wn + fj * 32 + l5;
#pragma unroll
        for (int vq = 0; vq < 4; vq++) {
          const int rb = mloc + wm + fi * 32 + vq * 8 + half * 4;
          __align__(8) __hip_bfloat16 t4[4];
#pragma unroll
          for (int r = 0; r < 4; r++)
            t4[r] = __float2bfloat16(acc[fi][fj][vq * 4 + r]);
          *(uint2*)(vtd + ((size_t)(bb * 128 + col)) * 2048 + rb) = *(uint2*)t4;
        }
      }
    }
    return;
  }

  __hip_bfloat16* dst;
  int dstride, dcol;
  if (n0 < 2048) {
    dst = qd; dstride = 2048; dcol = n0;
  } else {
    dst = kd; dstride = 128; dcol = 0;
  }
  // rope: head cols 0..63 live entirely in wn==0 waves; pair (c, c+32) =
  // (fj=0, fj=1) at the SAME lane and SAME reg index. inv_freq idx = l5.
  const bool dorope = (wn == 0);
  float invf = 0.f;
  if (dorope) invf = expf(-0.28782313662425574f * (float)l5);

#pragma unroll
  for (int fi = 0; fi < 2; fi++) {
#pragma unroll
    for (int v = 0; v < 16; v++) {
      const int row = m0 + wm + fi * 32 + (v & 3) + 8 * (v >> 2) + 4 * half;
      float o0 = acc[fi][0][v];   // col = wn + l5
      float o1 = acc[fi][1][v];   // col = wn + 32 + l5
      if (dorope) {
        const float pos = (float)(row & 2047);
        float s, c;
        __sincosf(pos * invf, &s, &c);
        const float a = o0, b = o1;
        o0 = a * c - b * s;
        o1 = a * s + b * c;
      }
      __hip_bfloat16* rp = dst + (size_t)row * dstride + dcol + wn + l5;
      rp[0]  = __float2bfloat16(o0);
      rp[32] = __float2bfloat16(o1);
    }
  }
}

// ---------------------------------------------------------------------------
// Output GEMM: fp32 + bias epilogue (32x32 C/D layout).
// ---------------------------------------------------------------------------
__global__ __launch_bounds__(256) void gemm_out(
    const __bf16* __restrict__ A, const __bf16* __restrict__ BT,
    float* __restrict__ C, const float* __restrict__ bias, int N, int K) {
  __shared__ __align__(16) __bf16 As[128 * 64];
  __shared__ __align__(16) __bf16 Bs[128 * 64];
  int bx, by;
  xcd_remap(bx, by);
  const int m0 = by * 128;
  const int n0 = bx * 128;
  f32x16 acc[2][2];
#pragma unroll
  for (int i = 0; i < 2; i++)
#pragma unroll
    for (int j = 0; j < 2; j++)
#pragma unroll
      for (int e = 0; e < 16; e++) acc[i][j][e] = 0.f;
  gemm_core32(A, BT, K, m0, n0, As, Bs, acc);

  const int tid = threadIdx.x;
  const int wave = tid >> 6;
  const int lane = tid & 63;
  const int l5 = lane & 31;
  const int half = lane >> 5;
  const int wm = (wave & 1) * 64;
  const int wn = (wave >> 1) * 64;
#pragma unroll
  for (int fj = 0; fj < 2; fj++) {
    const int col = n0 + wn + fj * 32 + l5;
    const float bv = bias[col];
#pragma unroll
    for (int fi = 0; fi < 2; fi++) {
#pragma unroll
      for (int v = 0; v < 16; v++) {
        const int row = m0 + wm + fi * 32 + (v & 3) + 8 * (v >> 2) + 4 * half;
        C[(size_t)row * N + col] = acc[fi][fj][v] + bv;
      }
    }
  }
}

// ---------------------------------------------------------------------------
// MFMA flash attention, 128-row Q tiles, fixed-max softmax (clamp 60).
// R8 version: K/V double-buffered with issue-early staging; ONE barrier per
// tile; setprio(1) around MFMA clusters; mask peel (t in {0,1,8,9} only).
// All LDS surfaces XOR-chunk-swizzled.
// ---------------------------------------------------------------------------
__global__ __launch_bounds__(256) void attn_mfma(
    const __bf16* __restrict__ qb,   // [B*2048][2048]
    const __bf16* __restrict__ kb,   // [B*2048][128]
    const __bf16* __restrict__ vtb,  // [B][128][2048]
    __hip_bfloat16* __restrict__ o)  // [B*2048][2048]
{
  __shared__ __align__(16) __bf16 Ks[2][4][64 * 32];   // 32 KB
  __shared__ __align__(16) __bf16 Vs[2][2][128 * 32];  // 32 KB
  __shared__ __align__(16) __bf16 Ps[4][2][2][512];    // 16 KB
  const int tid = threadIdx.x;
  const int wave = tid >> 6;
  const int lane = tid & 63;
  const int quad = lane >> 4;
  const int ln = lane & 15;
  const int bid = blockIdx.x;
  const int q0 = (bid & 15) * 128;
  const int h = (bid >> 4) & 15;
  const int b = bid >> 8;
  const int swr = (ln >> 1) & 3;               // read-side swizzle
  const int rdoff = (quad ^ swr) * 8;          // slot offset for b128 reads

  bf16x8 qf[2][4];
#pragma unroll
  for (int g = 0; g < 2; g++) {
    const __bf16* qrow =
        qb + ((size_t)(b * 2048 + q0 + wave * 32 + g * 16 + ln)) * 2048 + h * 128;
#pragma unroll
    for (int ks = 0; ks < 4; ks++)
      qf[g][ks] = *(const bf16x8*)(qrow + ks * 32 + quad * 8);
  }

  f32x4 oacc[2][8];
  const f32x4 zero = {0.f, 0.f, 0.f, 0.f};
#pragma unroll
  for (int g = 0; g < 2; g++)
#pragma unroll
    for (int nb = 0; nb < 8; nb++) oacc[g][nb] = zero;
  float li[2][4] = {{0.f, 0.f, 0.f, 0.f}, {0.f, 0.f, 0.f, 0.f}};
  const float scale = 0.08838834764831845f;  // 1/sqrt(128)

  const __bf16* kbase = kb + (size_t)b * 2048 * 128;
  const __bf16* vbase = vtb + (size_t)b * 128 * 2048;

  const int key4 = lane >> 2, uu = lane & 3;
  const int sw = (key4 >> 1) & 3;  // write-side swizzle: fetch chunk uu^sw

  auto stage_kv = [&](int t, int bufi) {
    const int jt = q0 - 512 + 64 * t;
#pragma unroll
    for (int i = 0; i < 4; ++i) {
      const int c = wave * 4 + i;
      const int ks = c & 3, keybase = (c >> 2) * 16;
      ASYNC_LD16(kbase + (size_t)(jt + keybase + key4) * 128 + ks * 32 +
                     (uu ^ sw) * 8,
                 &Ks[bufi][ks][keybase * 32]);
    }
#pragma unroll
    for (int i = 0; i < 4; ++i) {
      const int c = wave * 4 + i;
      const int p = c & 1, dbase = (c >> 1) * 16;
      ASYNC_LD16(vbase + (size_t)(dbase + key4) * 2048 + jt + p * 32 +
                     (uu ^ sw) * 8,
                 &Vs[bufi][p][dbase * 32]);
    }
  };

#define SOFTMAX_BODY(MASKED)                                                   \
  _Pragma("unroll") for (int g = 0; g < 2; g++)                                \
  _Pragma("unroll") for (int j = 0; j < 4; j++)                                \
  _Pragma("unroll") for (int r = 0; r < 4; r++) {                              \
    float v = sacc[g][j][r] * scale;                                           \
    if (MASKED) {                                                              \
      const int d0 = (wave * 32 + g * 16 + quad * 4 + r) - (j * 16 + ln);      \
      if (t <= 1 && d0 >= (t << 6)) v = -1e30f;                                \
      if (t >= 8 && d0 < ((t - 8) << 6)) v = -1e30f;                           \
    }                                                                          \
    v = fminf(v, 60.f);                                                        \
    const float p = __expf(v);                                                 \
    li[g][r] += p;                                                             \
    const int ch = (j & 1) * 2 + (ln >> 3);                                    \
    const int swp = (quad * 2 + (r >> 1)) & 3;                                 \
    Ps[wave][g][j >> 1][(quad * 4 + r) * 32 + (ch ^ swp) * 8 + (ln & 7)] =     \
        (__bf16)p;                                                             \
  }

  const int tstart = (q0 >= 512) ? 0 : (512 - q0) / 64;
  int cur = 0;
  stage_kv(tstart, 0);
  for (int t = tstart; t < 10; ++t) {
    __syncthreads();  // tile t resident in buf[cur]; buf[cur^1] free
    if (t + 1 < 10) stage_kv(t + 1, cur ^ 1);

    // S = Q K^T : 2 row groups x 4 col blocks x 4 k panels
    f32x4 sacc[2][4];
#pragma unroll
    for (int g = 0; g < 2; g++)
#pragma unroll
      for (int j = 0; j < 4; j++) sacc[g][j] = zero;
    __builtin_amdgcn_s_setprio(1);
#pragma unroll
    for (int j = 0; j < 4; j++)
#pragma unroll
      for (int ks = 0; ks < 4; ks++) {
        const bf16x8 kf =
            *(const bf16x8*)&Ks[cur][ks][(j * 16 + ln) * 32 + rdoff];
#pragma unroll
        for (int g = 0; g < 2; g++)
          sacc[g][j] = __builtin_amdgcn_mfma_f32_16x16x32_bf16(
              qf[g][ks], kf, sacc[g][j], 0, 0, 0);
      }
    __builtin_amdgcn_s_setprio(0);

    // scale + (mask) + exp -> Ps (swizzled); accumulate per-lane li
    if (t <= 1 || t >= 8) {
      SOFTMAX_BODY(1)
    } else {
      SOFTMAX_BODY(0)
    }

    const bf16x8 pf00 = *(const bf16x8*)&Ps[wave][0][0][ln * 32 + rdoff];
    const bf16x8 pf01 = *(const bf16x8*)&Ps[wave][0][1][ln * 32 + rdoff];
    const bf16x8 pf10 = *(const bf16x8*)&Ps[wave][1][0][ln * 32 + rdoff];
    const bf16x8 pf11 = *(const bf16x8*)&Ps[wave][1][1][ln * 32 + rdoff];
    __builtin_amdgcn_s_setprio(1);
#pragma unroll
    for (int nb = 0; nb < 8; nb++) {
      const bf16x8 vf0 =
          *(const bf16x8*)&Vs[cur][0][(nb * 16 + ln) * 32 + rdoff];
      const bf16x8 vf1 =
          *(const bf16x8*)&Vs[cur][1][(nb * 16 + ln) * 32 + rdoff];
      oacc[0][nb] = __builtin_amdgcn_mfma_f32_16x16x32_bf16(pf00, vf0,
                                                            oacc[0][nb], 0, 0, 0);
      oacc[0][nb] = __builtin_amdgcn_mfma_f32_16x16x32_bf16(pf01, vf1,
                                                            oacc[0][nb], 0, 0, 0);
      oacc[1][nb] = __builtin_amdgcn_mfma_f32_16x16x32_bf16(pf10, vf0,
                                                            oacc[1][nb], 0, 0, 0);
      oacc[1][nb] = __builtin_amdgcn_mfma_f32_16x16x32_bf16(pf11, vf1,
                                                            oacc[1][nb], 0, 0, 0);
    }
    __builtin_amdgcn_s_setprio(0);
    cur ^= 1;
  }
#undef SOFTMAX_BODY

#pragma unroll
  for (int off = 1; off < 16; off <<= 1)
#pragma unroll
    for (int g = 0; g < 2; g++)
#pragma unroll
      for (int r = 0; r < 4; r++) li[g][r] += __shfl_xor(li[g][r], off);

#pragma unroll
  for (int g = 0; g < 2; g++) {
    __hip_bfloat16* obase =
        o + ((size_t)(b * 2048 + q0 + wave * 32 + g * 16 + quad * 4)) * 2048 +
        h * 128 + ln;
#pragma unroll
    for (int r = 0; r < 4; r++) {
      const float inv = 1.0f / li[g][r];
#pragma unroll
      for (int nb = 0; nb < 8; nb++)
        obase[(size_t)r * 2048 + nb * 16] = __float2bfloat16(oacc[g][nb][r] * inv);
    }
  }
}

// ---------------------------------------------------------------------------
extern "C" void kernel_launch(void* const* d_in, const int* in_sizes, int n_in,
                              void* d_out, int out_size, void* d_ws,
                              size_t ws_size, hipStream_t stream) {
  const float* x = (const float*)d_in[0];
  const float* Wq = (const float*)d_in[1];
  const float* Wk = (const float*)d_in[2];
  const float* Wv = (const float*)d_in[3];
  const float* Wo = (const float*)d_in[4];
  const float* bo = (const float*)d_in[5];
  float* out = (float*)d_out;

  char* w = (char*)d_ws;
  auto alloc = [&](size_t bytes) {
    void* p = (void*)w;
    w += (bytes + 255) & ~(size_t)255;
    return p;
  };
  __bf16* xb = (__bf16*)alloc(4096ull * 2048 * 2);
  __hip_bfloat16* wqkvT = (__hip_bfloat16*)alloc(2304ull * 2048 * 2);
  __hip_bfloat16* woT = (__hip_bfloat16*)alloc(2048ull * 2048 * 2);
  __hip_bfloat16* qbuf = (__hip_bfloat16*)alloc(4096ull * 2048 * 2);
  __hip_bfloat16* kbuf = (__hip_bfloat16*)alloc(4096ull * 128 * 2);
  __hip_bfloat16* vtb = (__hip_bfloat16*)alloc(4096ull * 128 * 2);
  __hip_bfloat16* attnb = (__hip_bfloat16*)xb;  // alias: xb dead after gemm_qkv

  prep_all<<<16896, 256, 0, stream>>>(x, (__hip_bfloat16*)xb, Wq, Wk, Wv, Wo,
                                      wqkvT, woT);

  gemm_qkv<<<dim3(18, 32), 256, 0, stream>>>(xb, (const __bf16*)wqkvT, qbuf,
                                             kbuf, vtb, 2048);

  attn_mfma<<<512, 256, 0, stream>>>((const __bf16*)qbuf, (const __bf16*)kbuf,
                                     (const __bf16*)vtb, attnb);

  gemm_out<<<dim3(16, 32), 256, 0, stream>>>((const __bf16*)attnb,
                                             (const __bf16*)woT, out, bo, 2048,
                                             2048);
}

// Round 7
// 248.707 us; speedup vs baseline: 1.0457x; 1.0457x over previous
//
#include <hip/hip_runtime.h>
#include <hip/hip_bf16.h>
#include <stdint.h>

// ---------------------------------------------------------------------------
// LocalAttentionBlock: B=2, L=2048, D=2048, H=16 (MQA, 1 KV head), hd=128,
// rope dims=64, window=512.
// R11: GEMMs reverted to R9 (best measured: 64x128 tile, 4 waves, BK=64,
// 2-barrier core, XOR chunk swizzle, XCD remap; R10's 32x32-MFMA layout hit
// a structural 4-way bank conflict, 4.7M counted). attn rebuilt as 8 waves /
// 512 threads, QBLK=128 (wave owns 16 rows): 4 waves/SIMD resident (was 2)
// for latency hiding; same masks, same 80KB LDS, staging split 4-ways finer.
// ---------------------------------------------------------------------------

typedef float  f32x4  __attribute__((ext_vector_type(4)));
typedef __bf16 bf16x8 __attribute__((ext_vector_type(8)));

#define ASYNC_LD16(gp, lp)                                                     \
  __builtin_amdgcn_global_load_lds(                                            \
      (__attribute__((address_space(1))) void*)(gp),                           \
      (__attribute__((address_space(3))) void*)(lp), 16, 0, 0)

// ---------------------------------------------------------------------------
// Fused prep: blocks [0,8192) convert x -> bf16; blocks [8192,16896) do the
// four weight transposes (fp32 [R][C] -> bf16 [C][R]).
// ---------------------------------------------------------------------------
__global__ __launch_bounds__(256) void prep_all(
    const float* __restrict__ x, __hip_bfloat16* __restrict__ xb,
    const float* __restrict__ Wq, const float* __restrict__ Wk,
    const float* __restrict__ Wv, const float* __restrict__ Wo,
    __hip_bfloat16* __restrict__ wqkvT, __hip_bfloat16* __restrict__ woT) {
  __shared__ float t[32][33];
  int bid = blockIdx.x;
  if (bid < 8192) {
    const int i = bid * 256 + threadIdx.x;
    const float4 v = ((const float4*)x)[i];
    __align__(8) __hip_bfloat16 o[4] = {
        __float2bfloat16(v.x), __float2bfloat16(v.y),
        __float2bfloat16(v.z), __float2bfloat16(v.w)};
    *(uint2*)(xb + (size_t)i * 4) = *(uint2*)o;
    return;
  }
  bid -= 8192;
  const float* src;
  __hip_bfloat16* dst;
  int C, cb, rb;
  if (bid < 4096) {
    src = Wq; dst = wqkvT; C = 2048; cb = bid & 63; rb = bid >> 6;
  } else if (bid < 4352) {
    const int l = bid - 4096;
    src = Wk; dst = wqkvT + 2048ull * 2048; C = 128; cb = l & 3; rb = l >> 2;
  } else if (bid < 4608) {
    const int l = bid - 4352;
    src = Wv; dst = wqkvT + 2176ull * 2048; C = 128; cb = l & 3; rb = l >> 2;
  } else {
    const int l = bid - 4608;
    src = Wo; dst = woT; C = 2048; cb = l & 63; rb = l >> 6;
  }
  const int c0 = cb * 32, r0 = rb * 32;
  const int xx = threadIdx.x & 31, y = threadIdx.x >> 5;
#pragma unroll
  for (int i = 0; i < 32; i += 8)
    t[y + i][xx] = src[(size_t)(r0 + y + i) * C + c0 + xx];
  __syncthreads();
#pragma unroll
  for (int i = 0; i < 32; i += 8)
    dst[(size_t)(c0 + y + i) * 2048 + r0 + xx] = __float2bfloat16(t[xx][y + i]);
}

// Bijective XCD swizzle (grid % 8 == 0: 1152 and 1024).
__device__ __forceinline__ void xcd_remap(int& bx, int& by) {
  const int nwg = gridDim.x * gridDim.y;
  const int flat = blockIdx.y * gridDim.x + blockIdx.x;
  const int cpx = nwg >> 3;
  const int nid = (flat & 7) * cpx + (flat >> 3);
  bx = nid % gridDim.x;
  by = nid / gridDim.x;
}

// ---------------------------------------------------------------------------
// R9 GEMM core: 64x128 tile (M x N), 4 waves (256 thr), each wave 32x64
// (acc[2][4]). BK=64 as two 32-k panels. LDS: A 8 KB + B 16 KB, XOR chunk
// swizzle (measured zero conflicts). Load -> sync -> compute -> sync.
// ---------------------------------------------------------------------------
__device__ __forceinline__ void gemm_core64(const __bf16* __restrict__ A,
                                            const __bf16* __restrict__ BT,
                                            int K, int m0, int n0, __bf16* As,
                                            __bf16* Bs, f32x4 (&acc)[2][4]) {
  const int tid = threadIdx.x;
  const int wave = tid >> 6;          // 0..3
  const int lane = tid & 63;
  const int wm = (wave & 1) * 32;     // row group (0/32)
  const int wn = (wave >> 1) * 64;    // col group (0/64)
  const int ln = lane & 15;
  const int quad = lane >> 4;
  const int rdoff = (quad ^ ((ln >> 1) & 3)) * 8;

  size_t goffA[2];
  int ldsoffA[2];
#pragma unroll
  for (int i = 0; i < 2; i++) {
    const int cidx = (wave * 2 + i) * 64 + lane;  // [0,512)
    const int p = cidx >> 8;                      // k-panel 0/1
    const int pidx = cidx & 255;
    const int row = pidx >> 2;                    // [0,64)
    const int cc = pidx & 3;                      // chunk slot
    const int cg = cc ^ ((row >> 1) & 3);         // swizzled source chunk
    goffA[i] = (size_t)row * K + p * 32 + cg * 8;
    ldsoffA[i] = (wave * 2 + i) * 512;
  }
  size_t goffB[4];
  int ldsoffB[4];
#pragma unroll
  for (int i = 0; i < 4; i++) {
    const int cidx = (wave * 4 + i) * 64 + lane;  // [0,1024)
    const int p = cidx >> 9;
    const int pidx = cidx & 511;
    const int row = pidx >> 2;                    // [0,128)
    const int cc = pidx & 3;
    const int cg = cc ^ ((row >> 1) & 3);
    goffB[i] = (size_t)row * K + p * 32 + cg * 8;
    ldsoffB[i] = (wave * 4 + i) * 512;
  }
  const __bf16* Abase = A + (size_t)m0 * K;
  const __bf16* Bbase = BT + (size_t)n0 * K;

  for (int k0 = 0; k0 < K; k0 += 64) {
#pragma unroll
    for (int i = 0; i < 2; i++)
      ASYNC_LD16(Abase + k0 + goffA[i], As + ldsoffA[i]);
#pragma unroll
    for (int i = 0; i < 4; i++)
      ASYNC_LD16(Bbase + k0 + goffB[i], Bs + ldsoffB[i]);
    __syncthreads();
    bf16x8 af[2][2], bf[4][2];
#pragma unroll
    for (int i = 0; i < 2; i++)
#pragma unroll
      for (int p = 0; p < 2; p++)
        af[i][p] = *(const bf16x8*)&As[p * 2048 + (wm + i * 16 + ln) * 32 + rdoff];
#pragma unroll
    for (int j = 0; j < 4; j++)
#pragma unroll
      for (int p = 0; p < 2; p++)
        bf[j][p] = *(const bf16x8*)&Bs[p * 4096 + (wn + j * 16 + ln) * 32 + rdoff];
#pragma unroll
    for (int p = 0; p < 2; p++)
#pragma unroll
      for (int i = 0; i < 2; i++)
#pragma unroll
        for (int j = 0; j < 4; j++)
          acc[i][j] = __builtin_amdgcn_mfma_f32_16x16x32_bf16(af[i][p], bf[j][p],
                                                              acc[i][j], 0, 0, 0);
    __syncthreads();
  }
}

// ---------------------------------------------------------------------------
// QKV GEMM, fused epilogues. N=2304: n0<2048 -> q head (rope), n0==2048 -> k
// (rope), n0==2176 -> v written TRANSPOSED to vtd [b][128][2048].
// ---------------------------------------------------------------------------
__global__ __launch_bounds__(256) void gemm_qkv(
    const __bf16* __restrict__ A, const __bf16* __restrict__ BT,
    __hip_bfloat16* __restrict__ qd, __hip_bfloat16* __restrict__ kd,
    __hip_bfloat16* __restrict__ vtd, int K) {
  __shared__ __align__(16) __bf16 As[2 * 2048];
  __shared__ __align__(16) __bf16 Bs[2 * 4096];
  int bx, by;
  xcd_remap(bx, by);
  const int m0 = by * 64;
  const int n0 = bx * 128;
  f32x4 acc[2][4];
  const f32x4 zero = {0.f, 0.f, 0.f, 0.f};
#pragma unroll
  for (int i = 0; i < 2; i++)
#pragma unroll
    for (int j = 0; j < 4; j++) acc[i][j] = zero;
  gemm_core64(A, BT, K, m0, n0, As, Bs, acc);

  const int tid = threadIdx.x;
  const int wave = tid >> 6;
  const int lane = tid & 63;
  const int quad = lane >> 4;
  const int ln = lane & 15;
  const int wm = (wave & 1) * 32;
  const int wn = (wave >> 1) * 64;

  if (n0 == 2176) {  // V: transposed write, no rope
    const int bb = m0 >> 11;
    const int mloc = m0 & 2047;
#pragma unroll
    for (int i = 0; i < 2; i++) {
      const int rb = mloc + wm + i * 16 + quad * 4;
#pragma unroll
      for (int j = 0; j < 4; j++) {
        const int col = wn + j * 16 + ln;
        __align__(8) __hip_bfloat16 t4[4];
#pragma unroll
        for (int r = 0; r < 4; r++) t4[r] = __float2bfloat16(acc[i][j][r]);
        *(uint2*)(vtd + ((size_t)(bb * 128 + col)) * 2048 + rb) = *(uint2*)t4;
      }
    }
    return;
  }

  __hip_bfloat16* dst;
  int dstride, dcol;
  if (n0 < 2048) {
    dst = qd; dstride = 2048; dcol = n0;
  } else {
    dst = kd; dstride = 128; dcol = 0;
  }
  const bool dorope = (wn == 0);
  float invf0 = 0.f, invf1 = 0.f;
  if (dorope) {
    invf0 = expf(-0.28782313662425574f * (float)ln);          // d = ln
    invf1 = expf(-0.28782313662425574f * (float)(16 + ln));   // d = 16+ln
  }

#pragma unroll
  for (int i = 0; i < 2; i++) {
#pragma unroll
    for (int r = 0; r < 4; r++) {
      const int row = m0 + wm + i * 16 + quad * 4 + r;
      float o0 = acc[i][0][r], o1 = acc[i][1][r];
      float o2 = acc[i][2][r], o3 = acc[i][3][r];
      if (dorope) {
        const float pos = (float)(row & 2047);
        float s0, c0, s1, c1;
        __sincosf(pos * invf0, &s0, &c0);
        __sincosf(pos * invf1, &s1, &c1);
        const float a0 = o0, b0 = o2, a1 = o1, b1 = o3;
        o0 = a0 * c0 - b0 * s0;
        o2 = a0 * s0 + b0 * c0;
        o1 = a1 * c1 - b1 * s1;
        o3 = a1 * s1 + b1 * c1;
      }
      __hip_bfloat16* rp = dst + (size_t)row * dstride + dcol + wn + ln;
      rp[0]  = __float2bfloat16(o0);
      rp[16] = __float2bfloat16(o1);
      rp[32] = __float2bfloat16(o2);
      rp[48] = __float2bfloat16(o3);
    }
  }
}

// ---------------------------------------------------------------------------
// Output GEMM: fp32 + bias epilogue.
// ---------------------------------------------------------------------------
__global__ __launch_bounds__(256) void gemm_out(
    const __bf16* __restrict__ A, const __bf16* __restrict__ BT,
    float* __restrict__ C, const float* __restrict__ bias, int N, int K) {
  __shared__ __align__(16) __bf16 As[2 * 2048];
  __shared__ __align__(16) __bf16 Bs[2 * 4096];
  int bx, by;
  xcd_remap(bx, by);
  const int m0 = by * 64;
  const int n0 = bx * 128;
  f32x4 acc[2][4];
  const f32x4 zero = {0.f, 0.f, 0.f, 0.f};
#pragma unroll
  for (int i = 0; i < 2; i++)
#pragma unroll
    for (int j = 0; j < 4; j++) acc[i][j] = zero;
  gemm_core64(A, BT, K, m0, n0, As, Bs, acc);

  const int tid = threadIdx.x;
  const int wave = tid >> 6;
  const int lane = tid & 63;
  const int wm = (wave & 1) * 32;
  const int wn = (wave >> 1) * 64;
  const int lrow = lane & 15;
#pragma unroll
  for (int j = 0; j < 4; j++) {
    const int col = n0 + wn + j * 16 + lrow;
    const float bv = bias[col];
#pragma unroll
    for (int i = 0; i < 2; i++) {
#pragma unroll
      for (int r = 0; r < 4; r++) {
        const int row = m0 + wm + i * 16 + (lane >> 4) * 4 + r;
        C[(size_t)row * N + col] = acc[i][j][r] + bv;
      }
    }
  }
}

// ---------------------------------------------------------------------------
// MFMA flash attention, 128-row Q tiles, fixed-max softmax (clamp 60).
// R11: 8 waves / 512 threads, each wave owns 16 Q-rows (4 waves/SIMD resident
// for latency hiding). K/V double-buffered, issue-early staging, ONE barrier
// per tile, setprio around MFMA, mask peel (t in {0,1,8,9}). XOR swizzle on
// all LDS surfaces (zero-conflict pattern).
// ---------------------------------------------------------------------------
__global__ __launch_bounds__(512) void attn_mfma(
    const __bf16* __restrict__ qb,   // [B*2048][2048]
    const __bf16* __restrict__ kb,   // [B*2048][128]
    const __bf16* __restrict__ vtb,  // [B][128][2048]
    __hip_bfloat16* __restrict__ o)  // [B*2048][2048]
{
  __shared__ __align__(16) __bf16 Ks[2][4][64 * 32];   // 32 KB
  __shared__ __align__(16) __bf16 Vs[2][2][128 * 32];  // 32 KB
  __shared__ __align__(16) __bf16 Ps[8][2][512];       // 16 KB
  const int tid = threadIdx.x;
  const int w = tid >> 6;          // 0..7, wave owns rows [w*16, w*16+16)
  const int lane = tid & 63;
  const int quad = lane >> 4;
  const int ln = lane & 15;
  const int bid = blockIdx.x;
  const int q0 = (bid & 15) * 128;
  const int h = (bid >> 4) & 15;
  const int b = bid >> 8;
  const int swr = (ln >> 1) & 3;               // read-side swizzle
  const int rdoff = (quad ^ swr) * 8;          // slot offset for b128 reads

  bf16x8 qf[4];
  {
    const __bf16* qrow =
        qb + ((size_t)(b * 2048 + q0 + w * 16 + ln)) * 2048 + h * 128;
#pragma unroll
    for (int ks = 0; ks < 4; ks++)
      qf[ks] = *(const bf16x8*)(qrow + ks * 32 + quad * 8);
  }

  f32x4 oacc[8];
  const f32x4 zero = {0.f, 0.f, 0.f, 0.f};
#pragma unroll
  for (int nb = 0; nb < 8; nb++) oacc[nb] = zero;
  float li[4] = {0.f, 0.f, 0.f, 0.f};
  const float scale = 0.08838834764831845f;  // 1/sqrt(128)

  const __bf16* kbase = kb + (size_t)b * 2048 * 128;
  const __bf16* vbase = vtb + (size_t)b * 128 * 2048;

  const int key4 = lane >> 2, uu = lane & 3;
  const int sw = (key4 >> 1) & 3;  // write-side swizzle: fetch chunk uu^sw

  // 32 staging chunks (16 K + 16 V) split over 8 waves, 4 each.
  auto stage_kv = [&](int t, int bufi) {
    const int jt = q0 - 512 + 64 * t;
#pragma unroll
    for (int i = 0; i < 4; ++i) {
      const int g = w * 4 + i;     // 0..31
      if (g < 16) {                // K chunk g
        const int ks = g & 3, keybase = (g >> 2) * 16;
        ASYNC_LD16(kbase + (size_t)(jt + keybase + key4) * 128 + ks * 32 +
                       (uu ^ sw) * 8,
                   &Ks[bufi][ks][keybase * 32]);
      } else {                     // V chunk g-16
        const int c = g - 16;
        const int p = c & 1, dbase = (c >> 1) * 16;
        ASYNC_LD16(vbase + (size_t)(dbase + key4) * 2048 + jt + p * 32 +
                       (uu ^ sw) * 8,
                   &Vs[bufi][p][dbase * 32]);
      }
    }
  };

#define SOFTMAX_BODY(MASKED)                                                   \
  _Pragma("unroll") for (int j = 0; j < 4; j++)                                \
  _Pragma("unroll") for (int r = 0; r < 4; r++) {                              \
    float v = sacc[j][r] * scale;                                              \
    if (MASKED) {                                                              \
      const int d0 = (w * 16 + quad * 4 + r) - (j * 16 + ln);                  \
      if (t <= 1 && d0 >= (t << 6)) v = -1e30f;                                \
      if (t >= 8 && d0 < ((t - 8) << 6)) v = -1e30f;                           \
    }                                                                          \
    v = fminf(v, 60.f);                                                        \
    const float p = __expf(v);                                                 \
    li[r] += p;                                                                \
    const int ch = (j & 1) * 2 + (ln >> 3);                                    \
    const int swp = (quad * 2 + (r >> 1)) & 3;                                 \
    Ps[w][j >> 1][(quad * 4 + r) * 32 + (ch ^ swp) * 8 + (ln & 7)] =           \
        (__bf16)p;                                                             \
  }

  const int tstart = (q0 >= 512) ? 0 : (512 - q0) / 64;
  int cur = 0;
  stage_kv(tstart, 0);
  for (int t = tstart; t < 10; ++t) {
    __syncthreads();  // tile t resident in buf[cur]; buf[cur^1] free
    if (t + 1 < 10) stage_kv(t + 1, cur ^ 1);

    // S = Q K^T : 4 col blocks x 4 k panels
    f32x4 sacc[4];
#pragma unroll
    for (int j = 0; j < 4; j++) sacc[j] = zero;
    __builtin_amdgcn_s_setprio(1);
#pragma unroll
    for (int j = 0; j < 4; j++)
#pragma unroll
      for (int ks = 0; ks < 4; ks++) {
        const bf16x8 kf =
            *(const bf16x8*)&Ks[cur][ks][(j * 16 + ln) * 32 + rdoff];
        sacc[j] = __builtin_amdgcn_mfma_f32_16x16x32_bf16(qf[ks], kf, sacc[j],
                                                          0, 0, 0);
      }
    __builtin_amdgcn_s_setprio(0);

    // scale + (mask) + exp -> Ps (swizzled); accumulate per-lane li
    if (t <= 1 || t >= 8) {
      SOFTMAX_BODY(1)
    } else {
      SOFTMAX_BODY(0)
    }

    const bf16x8 pf0 = *(const bf16x8*)&Ps[w][0][ln * 32 + rdoff];
    const bf16x8 pf1 = *(const bf16x8*)&Ps[w][1][ln * 32 + rdoff];
    __builtin_amdgcn_s_setprio(1);
#pragma unroll
    for (int nb = 0; nb < 8; nb++) {
      const bf16x8 vf0 =
          *(const bf16x8*)&Vs[cur][0][(nb * 16 + ln) * 32 + rdoff];
      const bf16x8 vf1 =
          *(const bf16x8*)&Vs[cur][1][(nb * 16 + ln) * 32 + rdoff];
      oacc[nb] = __builtin_amdgcn_mfma_f32_16x16x32_bf16(pf0, vf0, oacc[nb],
                                                         0, 0, 0);
      oacc[nb] = __builtin_amdgcn_mfma_f32_16x16x32_bf16(pf1, vf1, oacc[nb],
                                                         0, 0, 0);
    }
    __builtin_amdgcn_s_setprio(0);
    cur ^= 1;
  }
#undef SOFTMAX_BODY

#pragma unroll
  for (int off = 1; off < 16; off <<= 1)
#pragma unroll
    for (int r = 0; r < 4; r++) li[r] += __shfl_xor(li[r], off);

  __hip_bfloat16* obase =
      o + ((size_t)(b * 2048 + q0 + w * 16 + quad * 4)) * 2048 + h * 128 + ln;
#pragma unroll
  for (int r = 0; r < 4; r++) {
    const float inv = 1.0f / li[r];
#pragma unroll
    for (int nb = 0; nb < 8; nb++)
      obase[(size_t)r * 2048 + nb * 16] = __float2bfloat16(oacc[nb][r] * inv);
  }
}

// ---------------------------------------------------------------------------
extern "C" void kernel_launch(void* const* d_in, const int* in_sizes, int n_in,
                              void* d_out, int out_size, void* d_ws,
                              size_t ws_size, hipStream_t stream) {
  const float* x = (const float*)d_in[0];
  const float* Wq = (const float*)d_in[1];
  const float* Wk = (const float*)d_in[2];
  const float* Wv = (const float*)d_in[3];
  const float* Wo = (const float*)d_in[4];
  const float* bo = (const float*)d_in[5];
  float* out = (float*)d_out;

  char* w = (char*)d_ws;
  auto alloc = [&](size_t bytes) {
    void* p = (void*)w;
    w += (bytes + 255) & ~(size_t)255;
    return p;
  };
  __bf16* xb = (__bf16*)alloc(4096ull * 2048 * 2);
  __hip_bfloat16* wqkvT = (__hip_bfloat16*)alloc(2304ull * 2048 * 2);
  __hip_bfloat16* woT = (__hip_bfloat16*)alloc(2048ull * 2048 * 2);
  __hip_bfloat16* qbuf = (__hip_bfloat16*)alloc(4096ull * 2048 * 2);
  __hip_bfloat16* kbuf = (__hip_bfloat16*)alloc(4096ull * 128 * 2);
  __hip_bfloat16* vtb = (__hip_bfloat16*)alloc(4096ull * 128 * 2);
  __hip_bfloat16* attnb = (__hip_bfloat16*)xb;  // alias: xb dead after gemm_qkv

  prep_all<<<16896, 256, 0, stream>>>(x, (__hip_bfloat16*)xb, Wq, Wk, Wv, Wo,
                                      wqkvT, woT);

  gemm_qkv<<<dim3(18, 64), 256, 0, stream>>>(xb, (const __bf16*)wqkvT, qbuf,
                                             kbuf, vtb, 2048);

  attn_mfma<<<512, 512, 0, stream>>>((const __bf16*)qbuf, (const __bf16*)kbuf,
                                     (const __bf16*)vtb, attnb);

  gemm_out<<<dim3(16, 64), 256, 0, stream>>>((const __bf16*)attnb,
                                             (const __bf16*)woT, out, bo, 2048,
                                             2048);
}